// Round 3
// baseline (4683.941 us; speedup 1.0000x reference)
//
#include <hip/hip_runtime.h>
#include <hip/hip_bf16.h>

typedef __bf16 bf16x8 __attribute__((ext_vector_type(8)));
typedef __bf16 bf16x4 __attribute__((ext_vector_type(4)));
typedef float  f32x4  __attribute__((ext_vector_type(4)));

static constexpr int BB   = 1024;   // batch
static constexpr int INF  = 256;    // IN
static constexpr int LATF = 512;    // LAT
static constexpr int HIDF = 1024;   // HID
static constexpr int OUTF = 64;     // OUT
static constexpr float DT = 0.05f;  // (T1-T0)/N_STEPS

__device__ __forceinline__ void gload_lds16(const __bf16* g, __bf16* l) {
    __builtin_amdgcn_global_load_lds(
        (const __attribute__((address_space(1))) void*)g,
        (__attribute__((address_space(3))) void*)l, 16, 0, 0);
}

__device__ __forceinline__ float tanh_fast(float x) {
    // tanh(x) = (e^2x - 1)/(e^2x + 1); abs err ~1e-7 near 0, fine (output is bf16-rounded)
    float e = __expf(2.0f * x);
    return (e - 1.0f) / (e + 1.0f);
}

__device__ __forceinline__ void spin_ge(const unsigned* p, unsigned tgt) {
    int guard = 0;
    while (__hip_atomic_load(p, __ATOMIC_ACQUIRE, __HIP_MEMORY_SCOPE_AGENT) < tgt) {
        __builtin_amdgcn_s_sleep(8);
        if (++guard > (1 << 23)) break;  // deterministic bailout; never hit when logic correct
    }
}

// ---------------- fused prep: x->bf16 + 3 weight transposes ----------------
__global__ __launch_bounds__(256)
void prep_k(const float* __restrict__ x, __bf16* __restrict__ xb,
            const float* __restrict__ W_in, __bf16* __restrict__ WinT,
            const float* __restrict__ W1, __bf16* __restrict__ W1T,
            const float* __restrict__ W2, __bf16* __restrict__ W2T) {
    const int b = blockIdx.x;
    const int tx = threadIdx.x, ty = threadIdx.y;
    if (b < 256) {
        const int i = b * 256 + ty * 32 + tx;
        float4 v = reinterpret_cast<const float4*>(x)[i];
        bf16x4 o;
        o[0] = (__bf16)v.x; o[1] = (__bf16)v.y; o[2] = (__bf16)v.z; o[3] = (__bf16)v.w;
        reinterpret_cast<bf16x4*>(xb)[i] = o;
        return;
    }
    const float* src; __bf16* dst; int R, C, tb;
    if (b < 384)      { src = W_in; dst = WinT; R = 256;  C = 512;  tb = b - 256; }
    else if (b < 896) { src = W1;   dst = W1T;  R = 512;  C = 1024; tb = b - 384; }
    else              { src = W2;   dst = W2T;  R = 1024; C = 512;  tb = b - 896; }
    __shared__ float tile[32][33];
    const int nbc = C / 32;
    const int c0 = (tb % nbc) * 32, r0 = (tb / nbc) * 32;
#pragma unroll
    for (int i = 0; i < 32; i += 8)
        tile[ty + i][tx] = src[(size_t)(r0 + ty + i) * C + (c0 + tx)];
    __syncthreads();
#pragma unroll
    for (int i = 0; i < 32; i += 8)
        dst[(size_t)(c0 + ty + i) * R + (r0 + tx)] = (__bf16)tile[tx][ty + i];
}

// ---------------- persistent ODE kernel ----------------
// 256 WGs (1/CU), 256 threads (4 waves). WG = (rb, slice): rb in [0,32) owns rows
// rb*32..+31; slice in [0,8): G1 cols = slice*128..+127 (HID), G2 cols = slice*64..+63 (LAT).
// Weights as persistent register B-fragments; A-tiles staged in 64KB LDS (swizzled);
// h/hacc in registers of waves kw==0; cross-WG sync via monotonic per-rb epoch counters.
__global__ __launch_bounds__(256, 1)
void ode_persist(const __bf16* __restrict__ xb, const __bf16* __restrict__ WinT,
                 const __bf16* __restrict__ W1T, const __bf16* __restrict__ W2T,
                 const float* __restrict__ b_in, const float* __restrict__ b1,
                 const float* __restrict__ wlast, const float* __restrict__ b2,
                 __bf16* __restrict__ zG, __bf16* __restrict__ gG,
                 float* __restrict__ hG, unsigned* __restrict__ cz,
                 unsigned* __restrict__ cg) {
    __shared__ __align__(16) unsigned char SL[65536];

    const int bid   = blockIdx.x;
    const int rb    = (bid & 7) * 4 + ((bid >> 3) & 3);  // same-rb WGs share an XCD (bid%8)
    const int slice = bid >> 5;
    const int r0 = rb * 32;
    const int c1 = slice * 128;   // G1 col base (HID)
    const int c2 = slice * 64;    // G2 col base (LAT)

    const int tid  = threadIdx.x;
    const int w    = tid >> 6;    // wave 0..3
    const int lane = tid & 63;
    const int fr   = lane & 15;   // frag row/col index
    const int kq   = lane >> 4;   // k-granule 0..3
    const int cw   = w & 1;       // G2 col-half
    const int kw   = w >> 1;      // G2 k-half

    // ---- persistent register B-fragments ----
    bf16x8 b1r[2][16];  // G1: cols c1+32w+16n+fr, K=512
#pragma unroll
    for (int n = 0; n < 2; ++n)
#pragma unroll
        for (int ks = 0; ks < 16; ++ks)
            b1r[n][ks] = *reinterpret_cast<const bf16x8*>(
                W1T + (size_t)(c1 + 32 * w + 16 * n + fr) * 512 + ks * 32 + kq * 8);

    bf16x8 b2r[2][16];  // G2: cols c2+32cw+16n+fr, K-half kw*512..+511
#pragma unroll
    for (int n = 0; n < 2; ++n)
#pragma unroll
        for (int ks = 0; ks < 16; ++ks)
            b2r[n][ks] = *reinterpret_cast<const bf16x8*>(
                W2T + (size_t)(c2 + 32 * cw + 16 * n + fr) * 1024 + kw * 512 + ks * 32 + kq * 8);

    // biases (constant over dyn loop)
    float b1v[2], wlv[2], b2v[2], binv[2];
#pragma unroll
    for (int n = 0; n < 2; ++n) {
        const int colg = c1 + 32 * w + 16 * n + fr;
        b1v[n] = b1[colg];
        wlv[n] = wlast[colg];
        const int colk = c2 + 32 * cw + 16 * n + fr;
        b2v[n] = b2[colk];
        binv[n] = b_in[colk];
    }

    f32x4 hr[2][2], ha[2][2];  // h, h_acc (meaningful on kw==0 waves)

    // =========== h0 = tanh(x @ W_in + b_in) ===========
    {
        // stage xb tile [32 rows][256 k] = 16KB, swizzled source
#pragma unroll
        for (int i = 0; i < 4; ++i) {
            const int idx = w * 4 + i;
            const int row = idx * 2 + (lane >> 5);
            const int gam = (lane & 31) ^ (row & 7);
            gload_lds16(xb + (size_t)(r0 + row) * 256 + gam * 8,
                        (__bf16*)(SL + (size_t)idx * 1024));
        }
        // transient W_in B-frags (K-half = 128)
        bf16x8 winr[2][4];
#pragma unroll
        for (int n = 0; n < 2; ++n)
#pragma unroll
            for (int ks = 0; ks < 4; ++ks)
                winr[n][ks] = *reinterpret_cast<const bf16x8*>(
                    WinT + (size_t)(c2 + 32 * cw + 16 * n + fr) * 256 + kw * 128 + ks * 32 + kq * 8);
        __syncthreads();

        f32x4 acc[2][2];
#pragma unroll
        for (int mi = 0; mi < 2; ++mi)
#pragma unroll
            for (int n = 0; n < 2; ++n) acc[mi][n] = f32x4{0.f, 0.f, 0.f, 0.f};
#pragma unroll
        for (int ks = 0; ks < 4; ++ks) {
            bf16x8 a[2];
#pragma unroll
            for (int mi = 0; mi < 2; ++mi) {
                const int rowA = 16 * mi + fr;
                const int gk = kw * 16 + ks * 4 + kq;
                a[mi] = *reinterpret_cast<const bf16x8*>(
                    SL + (size_t)rowA * 512 + ((gk ^ (rowA & 7)) << 4));
            }
#pragma unroll
            for (int mi = 0; mi < 2; ++mi)
#pragma unroll
                for (int n = 0; n < 2; ++n)
                    acc[mi][n] = __builtin_amdgcn_mfma_f32_16x16x32_bf16(a[mi], winr[n][ks],
                                                                         acc[mi][n], 0, 0, 0);
        }
        __syncthreads();
        if (kw == 1) {
#pragma unroll
            for (int mi = 0; mi < 2; ++mi)
#pragma unroll
                for (int n = 0; n < 2; ++n)
                    *reinterpret_cast<f32x4*>(SL + cw * 4096 + ((mi * 2 + n) * 64 + lane) * 16) =
                        acc[mi][n];
        }
        __syncthreads();
        if (kw == 0) {
#pragma unroll
            for (int mi = 0; mi < 2; ++mi)
#pragma unroll
                for (int n = 0; n < 2; ++n) {
                    f32x4 part = *reinterpret_cast<const f32x4*>(
                        SL + cw * 4096 + ((mi * 2 + n) * 64 + lane) * 16);
#pragma unroll
                    for (int j = 0; j < 4; ++j) {
                        const float v = tanh_fast(acc[mi][n][j] + part[j] + binv[n]);
                        hr[mi][n][j] = v;
                        zG[(size_t)(r0 + 16 * mi + kq * 4 + j) * 512 +
                           (c2 + 32 * cw + 16 * n + fr)] = (__bf16)v;
                    }
                }
        }
        __syncthreads();
        if (tid == 0)
            __hip_atomic_fetch_add(&cz[rb], 1u, __ATOMIC_RELEASE, __HIP_MEMORY_SCOPE_AGENT);
    }

    // =========== 80 dyn evaluations (20 RK4 steps x 4) ===========
    for (int it = 0; it < 80; ++it) {
        const int s4 = it >> 2, st = it & 3;
        const float t = DT * (float)s4 + ((st == 0) ? 0.f : (st == 3) ? DT : 0.5f * DT);

        // ---- G1: g = tanh(z @ W1 + b1 + t*wl), this WG's 128 cols ----
        spin_ge(&cz[rb], (unsigned)(8 * (it + 1)));
        // stage z tile [32][512] = 32KB
#pragma unroll
        for (int i = 0; i < 8; ++i) {
            const int row = w * 8 + i;
            const int gam = lane ^ (row & 7);
            gload_lds16(zG + (size_t)(r0 + row) * 512 + gam * 8,
                        (__bf16*)(SL + (size_t)row * 1024));
        }
        __syncthreads();
        {
            f32x4 acc[2][2];
#pragma unroll
            for (int mi = 0; mi < 2; ++mi)
#pragma unroll
                for (int n = 0; n < 2; ++n) acc[mi][n] = f32x4{0.f, 0.f, 0.f, 0.f};
#pragma unroll
            for (int ks = 0; ks < 16; ++ks) {
                bf16x8 a[2];
#pragma unroll
                for (int mi = 0; mi < 2; ++mi) {
                    const int rowA = 16 * mi + fr;
                    const int gk = ks * 4 + kq;
                    a[mi] = *reinterpret_cast<const bf16x8*>(
                        SL + (size_t)rowA * 1024 + ((gk ^ (rowA & 7)) << 4));
                }
#pragma unroll
                for (int mi = 0; mi < 2; ++mi)
#pragma unroll
                    for (int n = 0; n < 2; ++n)
                        acc[mi][n] = __builtin_amdgcn_mfma_f32_16x16x32_bf16(a[mi], b1r[n][ks],
                                                                             acc[mi][n], 0, 0, 0);
            }
            // epilogue: tanh + store g (bf16)
#pragma unroll
            for (int mi = 0; mi < 2; ++mi)
#pragma unroll
                for (int n = 0; n < 2; ++n)
#pragma unroll
                    for (int j = 0; j < 4; ++j) {
                        const float gv = tanh_fast(acc[mi][n][j] + b1v[n] + t * wlv[n]);
                        gG[(size_t)(r0 + 16 * mi + kq * 4 + j) * 1024 +
                           (c1 + 32 * w + 16 * n + fr)] = (__bf16)gv;
                    }
        }
        __syncthreads();
        if (tid == 0)
            __hip_atomic_fetch_add(&cg[rb], 1u, __ATOMIC_RELEASE, __HIP_MEMORY_SCOPE_AGENT);

        // ---- G2: k = g @ W2 + b2, this WG's 64 cols; RK4 update in regs ----
        spin_ge(&cg[rb], (unsigned)(8 * (it + 1)));
        // stage g tile [32][1024] = 64KB
#pragma unroll
        for (int i = 0; i < 16; ++i) {
            const int idx = w * 16 + i;
            const int row = idx >> 1;
            const int p = ((idx & 1) << 6) | lane;
            const int gam = p ^ (row & 7);
            gload_lds16(gG + (size_t)(r0 + row) * 1024 + gam * 8,
                        (__bf16*)(SL + (size_t)idx * 1024));
        }
        __syncthreads();
        {
            f32x4 acc[2][2];
#pragma unroll
            for (int mi = 0; mi < 2; ++mi)
#pragma unroll
                for (int n = 0; n < 2; ++n) acc[mi][n] = f32x4{0.f, 0.f, 0.f, 0.f};
#pragma unroll
            for (int ks = 0; ks < 16; ++ks) {
                bf16x8 a[2];
#pragma unroll
                for (int mi = 0; mi < 2; ++mi) {
                    const int rowA = 16 * mi + fr;
                    const int gk = kw * 64 + ks * 4 + kq;
                    a[mi] = *reinterpret_cast<const bf16x8*>(
                        SL + (size_t)rowA * 2048 + ((gk ^ (rowA & 7)) << 4));
                }
#pragma unroll
                for (int mi = 0; mi < 2; ++mi)
#pragma unroll
                    for (int n = 0; n < 2; ++n)
                        acc[mi][n] = __builtin_amdgcn_mfma_f32_16x16x32_bf16(a[mi], b2r[n][ks],
                                                                             acc[mi][n], 0, 0, 0);
            }
            __syncthreads();
            if (kw == 1) {
#pragma unroll
                for (int mi = 0; mi < 2; ++mi)
#pragma unroll
                    for (int n = 0; n < 2; ++n)
                        *reinterpret_cast<f32x4*>(SL + cw * 4096 + ((mi * 2 + n) * 64 + lane) * 16) =
                            acc[mi][n];
            }
            __syncthreads();
            if (kw == 0) {
                const float wA = (st == 0 || st == 3) ? (DT / 6.0f) : (DT / 3.0f);
                const float cZ = (st < 2) ? (0.5f * DT) : DT;
#pragma unroll
                for (int mi = 0; mi < 2; ++mi)
#pragma unroll
                    for (int n = 0; n < 2; ++n) {
                        f32x4 part = *reinterpret_cast<const f32x4*>(
                            SL + cw * 4096 + ((mi * 2 + n) * 64 + lane) * 16);
#pragma unroll
                        for (int j = 0; j < 4; ++j) {
                            const float kv = acc[mi][n][j] + part[j] + b2v[n];
                            float zv;
                            if (st == 0) {
                                ha[mi][n][j] = hr[mi][n][j] + wA * kv;
                                zv = hr[mi][n][j] + cZ * kv;
                            } else if (st < 3) {
                                ha[mi][n][j] += wA * kv;
                                zv = hr[mi][n][j] + cZ * kv;
                            } else {
                                hr[mi][n][j] = ha[mi][n][j] + wA * kv;
                                zv = hr[mi][n][j];
                            }
                            zG[(size_t)(r0 + 16 * mi + kq * 4 + j) * 512 +
                               (c2 + 32 * cw + 16 * n + fr)] = (__bf16)zv;
                        }
                    }
            }
        }
        __syncthreads();
        if (tid == 0)
            __hip_atomic_fetch_add(&cz[rb], 1u, __ATOMIC_RELEASE, __HIP_MEMORY_SCOPE_AGENT);
    }

    // final h -> global (fp32)
    if (kw == 0) {
#pragma unroll
        for (int mi = 0; mi < 2; ++mi)
#pragma unroll
            for (int n = 0; n < 2; ++n)
#pragma unroll
                for (int j = 0; j < 4; ++j)
                    hG[(size_t)(r0 + 16 * mi + kq * 4 + j) * 512 +
                       (c2 + 32 * cw + 16 * n + fr)] = hr[mi][n][j];
    }
}

// ---------------- out = h[:, :256] @ W_out + b_out (fp32) ----------------
__global__ __launch_bounds__(256)
void out_k(const float* __restrict__ h, const float* __restrict__ Wout,
           const float* __restrict__ bout, float* __restrict__ out) {
    const int col = threadIdx.x & 63;
    const int rg  = threadIdx.x >> 6;
    const int r0  = blockIdx.x * 16 + rg * 4;
    float a0 = 0.f, a1 = 0.f, a2 = 0.f, a3 = 0.f;
    for (int k = 0; k < 256; ++k) {
        const float w = Wout[k * OUTF + col];
        a0 += h[(r0 + 0) * LATF + k] * w;
        a1 += h[(r0 + 1) * LATF + k] * w;
        a2 += h[(r0 + 2) * LATF + k] * w;
        a3 += h[(r0 + 3) * LATF + k] * w;
    }
    const float b = bout[col];
    out[(r0 + 0) * OUTF + col] = a0 + b;
    out[(r0 + 1) * OUTF + col] = a1 + b;
    out[(r0 + 2) * OUTF + col] = a2 + b;
    out[(r0 + 3) * OUTF + col] = a3 + b;
}

extern "C" void kernel_launch(void* const* d_in, const int* in_sizes, int n_in,
                              void* d_out, int out_size, void* d_ws, size_t ws_size,
                              hipStream_t stream) {
    const float* x     = (const float*)d_in[0];
    const float* W_in  = (const float*)d_in[1];
    const float* b_in  = (const float*)d_in[2];
    const float* W1    = (const float*)d_in[3];   // (LAT+1, HID)
    const float* b1    = (const float*)d_in[4];
    const float* W2    = (const float*)d_in[5];   // (HID, LAT)
    const float* b2    = (const float*)d_in[6];
    const float* W_out = (const float*)d_in[7];   // (LAT/2, OUT)
    const float* b_out = (const float*)d_in[8];
    float* out = (float*)d_out;

    char* ws = (char*)d_ws;
    size_t off = 0;
    auto alloc = [&](size_t bytes) {
        void* p = ws + off;
        off += (bytes + 255) & ~(size_t)255;
        return p;
    };
    __bf16* xb   = (__bf16*)alloc((size_t)BB * INF * 2);
    __bf16* WinT = (__bf16*)alloc((size_t)LATF * INF * 2);   // [LAT][IN]
    __bf16* W1T  = (__bf16*)alloc((size_t)HIDF * LATF * 2);  // [HID][LAT]
    __bf16* W2T  = (__bf16*)alloc((size_t)LATF * HIDF * 2);  // [LAT][HID]
    float*  h    = (float*)alloc((size_t)BB * LATF * 4);
    __bf16* zbuf = (__bf16*)alloc((size_t)BB * LATF * 2);
    __bf16* gbuf = (__bf16*)alloc((size_t)BB * HIDF * 2);
    unsigned* cnts = (unsigned*)alloc(256);                  // cz[32] + cg[32]
    if (off > ws_size) return;

    unsigned* cz = cnts;
    unsigned* cg = cnts + 32;

    hipMemsetAsync(cnts, 0, 256, stream);
    prep_k<<<1408, dim3(32, 8), 0, stream>>>(x, xb, W_in, WinT, W1, W1T, W2, W2T);

    const float* w1last = W1 + (size_t)LATF * HIDF;  // row 512 of W1 (t coefficients)

    ode_persist<<<256, 256, 0, stream>>>(xb, WinT, W1T, W2T, b_in, b1, w1last, b2,
                                         zbuf, gbuf, h, cz, cg);

    out_k<<<BB / 16, 256, 0, stream>>>(h, W_out, b_out, out);
}

// Round 4
// 1825.662 us; speedup vs baseline: 2.5656x; 2.5656x over previous
//
#include <hip/hip_runtime.h>
#include <hip/hip_bf16.h>

typedef __bf16 bf16x8 __attribute__((ext_vector_type(8)));
typedef __bf16 bf16x4 __attribute__((ext_vector_type(4)));
typedef float  f32x4  __attribute__((ext_vector_type(4)));

static constexpr int BB   = 1024;   // batch
static constexpr int INF  = 256;    // IN
static constexpr int LATF = 512;    // LAT
static constexpr int HIDF = 1024;   // HID
static constexpr int OUTF = 64;     // OUT
static constexpr float DT = 0.05f;  // (T1-T0)/N_STEPS

__device__ __forceinline__ void gload_lds16(const __bf16* g, __bf16* l) {
    __builtin_amdgcn_global_load_lds(
        (const __attribute__((address_space(1))) void*)g,
        (__attribute__((address_space(3))) void*)l, 16, 0, 0);
}

__device__ __forceinline__ float tanh_fast(float x) {
    float e = __expf(2.0f * x);
    return (e - 1.0f) / (e + 1.0f);
}

// single-thread poll: RELAXED loads (no per-iteration cache maintenance),
// one ACQUIRE fence once the target is reached. Caller must __syncthreads() after.
__device__ __forceinline__ void spin_ge_t0(const unsigned* p, unsigned tgt) {
    int guard = 0;
    while (__hip_atomic_load(p, __ATOMIC_RELAXED, __HIP_MEMORY_SCOPE_AGENT) < tgt) {
        __builtin_amdgcn_s_sleep(4);
        if (++guard > (1 << 23)) break;  // deterministic bailout; never hit when logic correct
    }
    __builtin_amdgcn_fence(__ATOMIC_ACQUIRE, "agent");
}

// ---------------- fused prep: x->bf16 + 3 weight transposes ----------------
__global__ __launch_bounds__(256)
void prep_k(const float* __restrict__ x, __bf16* __restrict__ xb,
            const float* __restrict__ W_in, __bf16* __restrict__ WinT,
            const float* __restrict__ W1, __bf16* __restrict__ W1T,
            const float* __restrict__ W2, __bf16* __restrict__ W2T) {
    const int b = blockIdx.x;
    const int tx = threadIdx.x, ty = threadIdx.y;
    if (b < 256) {
        const int i = b * 256 + ty * 32 + tx;
        float4 v = reinterpret_cast<const float4*>(x)[i];
        bf16x4 o;
        o[0] = (__bf16)v.x; o[1] = (__bf16)v.y; o[2] = (__bf16)v.z; o[3] = (__bf16)v.w;
        reinterpret_cast<bf16x4*>(xb)[i] = o;
        return;
    }
    const float* src; __bf16* dst; int R, C, tb;
    if (b < 384)      { src = W_in; dst = WinT; R = 256;  C = 512;  tb = b - 256; }
    else if (b < 896) { src = W1;   dst = W1T;  R = 512;  C = 1024; tb = b - 384; }
    else              { src = W2;   dst = W2T;  R = 1024; C = 512;  tb = b - 896; }
    __shared__ float tile[32][33];
    const int nbc = C / 32;
    const int c0 = (tb % nbc) * 32, r0 = (tb / nbc) * 32;
#pragma unroll
    for (int i = 0; i < 32; i += 8)
        tile[ty + i][tx] = src[(size_t)(r0 + ty + i) * C + (c0 + tx)];
    __syncthreads();
#pragma unroll
    for (int i = 0; i < 32; i += 8)
        dst[(size_t)(c0 + ty + i) * R + (r0 + tx)] = (__bf16)tile[tx][ty + i];
}

// ---------------- persistent ODE kernel ----------------
// 256 WGs (1/CU), 256 threads (4 waves). WG = (rb, slice): rb in [0,32) owns rows
// rb*32..+31; slice in [0,8): G1 cols = slice*128..+127 (HID), G2 cols = slice*64..+63 (LAT).
// Weights as persistent register B-fragments; A-tiles staged in 64KB LDS (swizzled);
// h/hacc in registers of waves kw==0; cross-WG sync via monotonic per-rb epoch counters
// (tid0-only relaxed poll + single acquire fence — round-3's all-thread ACQUIRE
// polling was a buffer_inv storm: MfmaUtil 1.4%).
__global__ __launch_bounds__(256, 1)
void ode_persist(const __bf16* __restrict__ xb, const __bf16* __restrict__ WinT,
                 const __bf16* __restrict__ W1T, const __bf16* __restrict__ W2T,
                 const float* __restrict__ b_in, const float* __restrict__ b1,
                 const float* __restrict__ wlast, const float* __restrict__ b2,
                 __bf16* __restrict__ zG, __bf16* __restrict__ gG,
                 float* __restrict__ hG, unsigned* __restrict__ cz,
                 unsigned* __restrict__ cg) {
    __shared__ __align__(16) unsigned char SL[65536];

    const int bid   = blockIdx.x;
    const int rb    = (bid & 7) * 4 + ((bid >> 3) & 3);  // same-rb WGs share an XCD (bid%8)
    const int slice = bid >> 5;
    const int r0 = rb * 32;
    const int c1 = slice * 128;   // G1 col base (HID)
    const int c2 = slice * 64;    // G2 col base (LAT)

    const int tid  = threadIdx.x;
    const int w    = tid >> 6;    // wave 0..3
    const int lane = tid & 63;
    const int fr   = lane & 15;   // frag row/col index
    const int kq   = lane >> 4;   // k-granule 0..3
    const int cw   = w & 1;       // G2 col-half
    const int kw   = w >> 1;      // G2 k-half

    // ---- persistent register B-fragments ----
    bf16x8 b1r[2][16];  // G1: cols c1+32w+16n+fr, K=512
#pragma unroll
    for (int n = 0; n < 2; ++n)
#pragma unroll
        for (int ks = 0; ks < 16; ++ks)
            b1r[n][ks] = *reinterpret_cast<const bf16x8*>(
                W1T + (size_t)(c1 + 32 * w + 16 * n + fr) * 512 + ks * 32 + kq * 8);

    bf16x8 b2r[2][16];  // G2: cols c2+32cw+16n+fr, K-half kw*512..+511
#pragma unroll
    for (int n = 0; n < 2; ++n)
#pragma unroll
        for (int ks = 0; ks < 16; ++ks)
            b2r[n][ks] = *reinterpret_cast<const bf16x8*>(
                W2T + (size_t)(c2 + 32 * cw + 16 * n + fr) * 1024 + kw * 512 + ks * 32 + kq * 8);

    // biases (constant over dyn loop)
    float b1v[2], wlv[2], b2v[2], binv[2];
#pragma unroll
    for (int n = 0; n < 2; ++n) {
        const int colg = c1 + 32 * w + 16 * n + fr;
        b1v[n] = b1[colg];
        wlv[n] = wlast[colg];
        const int colk = c2 + 32 * cw + 16 * n + fr;
        b2v[n] = b2[colk];
        binv[n] = b_in[colk];
    }

    f32x4 hr[2][2], ha[2][2];  // h, h_acc (meaningful on kw==0 waves)

    // =========== h0 = tanh(x @ W_in + b_in) ===========
    {
#pragma unroll
        for (int i = 0; i < 4; ++i) {
            const int idx = w * 4 + i;
            const int row = idx * 2 + (lane >> 5);
            const int gam = (lane & 31) ^ (row & 7);
            gload_lds16(xb + (size_t)(r0 + row) * 256 + gam * 8,
                        (__bf16*)(SL + (size_t)idx * 1024));
        }
        bf16x8 winr[2][4];
#pragma unroll
        for (int n = 0; n < 2; ++n)
#pragma unroll
            for (int ks = 0; ks < 4; ++ks)
                winr[n][ks] = *reinterpret_cast<const bf16x8*>(
                    WinT + (size_t)(c2 + 32 * cw + 16 * n + fr) * 256 + kw * 128 + ks * 32 + kq * 8);
        __syncthreads();

        f32x4 acc[2][2];
#pragma unroll
        for (int mi = 0; mi < 2; ++mi)
#pragma unroll
            for (int n = 0; n < 2; ++n) acc[mi][n] = f32x4{0.f, 0.f, 0.f, 0.f};
#pragma unroll
        for (int ks = 0; ks < 4; ++ks) {
            bf16x8 a[2];
#pragma unroll
            for (int mi = 0; mi < 2; ++mi) {
                const int rowA = 16 * mi + fr;
                const int gk = kw * 16 + ks * 4 + kq;
                a[mi] = *reinterpret_cast<const bf16x8*>(
                    SL + (size_t)rowA * 512 + ((gk ^ (rowA & 7)) << 4));
            }
#pragma unroll
            for (int mi = 0; mi < 2; ++mi)
#pragma unroll
                for (int n = 0; n < 2; ++n)
                    acc[mi][n] = __builtin_amdgcn_mfma_f32_16x16x32_bf16(a[mi], winr[n][ks],
                                                                         acc[mi][n], 0, 0, 0);
        }
        __syncthreads();
        if (kw == 1) {
#pragma unroll
            for (int mi = 0; mi < 2; ++mi)
#pragma unroll
                for (int n = 0; n < 2; ++n)
                    *reinterpret_cast<f32x4*>(SL + cw * 4096 + ((mi * 2 + n) * 64 + lane) * 16) =
                        acc[mi][n];
        }
        __syncthreads();
        if (kw == 0) {
#pragma unroll
            for (int mi = 0; mi < 2; ++mi)
#pragma unroll
                for (int n = 0; n < 2; ++n) {
                    f32x4 part = *reinterpret_cast<const f32x4*>(
                        SL + cw * 4096 + ((mi * 2 + n) * 64 + lane) * 16);
#pragma unroll
                    for (int j = 0; j < 4; ++j) {
                        const float v = tanh_fast(acc[mi][n][j] + part[j] + binv[n]);
                        hr[mi][n][j] = v;
                        zG[(size_t)(r0 + 16 * mi + kq * 4 + j) * 512 +
                           (c2 + 32 * cw + 16 * n + fr)] = (__bf16)v;
                    }
                }
        }
        __syncthreads();
        if (tid == 0)
            __hip_atomic_fetch_add(&cz[rb], 1u, __ATOMIC_RELEASE, __HIP_MEMORY_SCOPE_AGENT);
    }

    // =========== 80 dyn evaluations (20 RK4 steps x 4) ===========
    for (int it = 0; it < 80; ++it) {
        const int s4 = it >> 2, st = it & 3;
        const float t = DT * (float)s4 + ((st == 0) ? 0.f : (st == 3) ? DT : 0.5f * DT);

        // ---- G1: g = tanh(z @ W1 + b1 + t*wl), this WG's 128 cols ----
        if (tid == 0) spin_ge_t0(&cz[rb], (unsigned)(8 * (it + 1)));
        __syncthreads();
#pragma unroll
        for (int i = 0; i < 8; ++i) {
            const int row = w * 8 + i;
            const int gam = lane ^ (row & 7);
            gload_lds16(zG + (size_t)(r0 + row) * 512 + gam * 8,
                        (__bf16*)(SL + (size_t)row * 1024));
        }
        __syncthreads();
        {
            f32x4 acc[2][2];
#pragma unroll
            for (int mi = 0; mi < 2; ++mi)
#pragma unroll
                for (int n = 0; n < 2; ++n) acc[mi][n] = f32x4{0.f, 0.f, 0.f, 0.f};
#pragma unroll
            for (int ks = 0; ks < 16; ++ks) {
                bf16x8 a[2];
#pragma unroll
                for (int mi = 0; mi < 2; ++mi) {
                    const int rowA = 16 * mi + fr;
                    const int gk = ks * 4 + kq;
                    a[mi] = *reinterpret_cast<const bf16x8*>(
                        SL + (size_t)rowA * 1024 + ((gk ^ (rowA & 7)) << 4));
                }
#pragma unroll
                for (int mi = 0; mi < 2; ++mi)
#pragma unroll
                    for (int n = 0; n < 2; ++n)
                        acc[mi][n] = __builtin_amdgcn_mfma_f32_16x16x32_bf16(a[mi], b1r[n][ks],
                                                                             acc[mi][n], 0, 0, 0);
            }
#pragma unroll
            for (int mi = 0; mi < 2; ++mi)
#pragma unroll
                for (int n = 0; n < 2; ++n)
#pragma unroll
                    for (int j = 0; j < 4; ++j) {
                        const float gv = tanh_fast(acc[mi][n][j] + b1v[n] + t * wlv[n]);
                        gG[(size_t)(r0 + 16 * mi + kq * 4 + j) * 1024 +
                           (c1 + 32 * w + 16 * n + fr)] = (__bf16)gv;
                    }
        }
        __syncthreads();
        if (tid == 0) {
            __hip_atomic_fetch_add(&cg[rb], 1u, __ATOMIC_RELEASE, __HIP_MEMORY_SCOPE_AGENT);
            // ---- wait for all g slices ----
            spin_ge_t0(&cg[rb], (unsigned)(8 * (it + 1)));
        }
        __syncthreads();
        // stage g tile [32][1024] = 64KB
#pragma unroll
        for (int i = 0; i < 16; ++i) {
            const int idx = w * 16 + i;
            const int row = idx >> 1;
            const int p = ((idx & 1) << 6) | lane;
            const int gam = p ^ (row & 7);
            gload_lds16(gG + (size_t)(r0 + row) * 1024 + gam * 8,
                        (__bf16*)(SL + (size_t)idx * 1024));
        }
        __syncthreads();
        {
            f32x4 acc[2][2];
#pragma unroll
            for (int mi = 0; mi < 2; ++mi)
#pragma unroll
                for (int n = 0; n < 2; ++n) acc[mi][n] = f32x4{0.f, 0.f, 0.f, 0.f};
#pragma unroll
            for (int ks = 0; ks < 16; ++ks) {
                bf16x8 a[2];
#pragma unroll
                for (int mi = 0; mi < 2; ++mi) {
                    const int rowA = 16 * mi + fr;
                    const int gk = kw * 64 + ks * 4 + kq;
                    a[mi] = *reinterpret_cast<const bf16x8*>(
                        SL + (size_t)rowA * 2048 + ((gk ^ (rowA & 7)) << 4));
                }
#pragma unroll
                for (int mi = 0; mi < 2; ++mi)
#pragma unroll
                    for (int n = 0; n < 2; ++n)
                        acc[mi][n] = __builtin_amdgcn_mfma_f32_16x16x32_bf16(a[mi], b2r[n][ks],
                                                                             acc[mi][n], 0, 0, 0);
            }
            __syncthreads();
            if (kw == 1) {
#pragma unroll
                for (int mi = 0; mi < 2; ++mi)
#pragma unroll
                    for (int n = 0; n < 2; ++n)
                        *reinterpret_cast<f32x4*>(SL + cw * 4096 + ((mi * 2 + n) * 64 + lane) * 16) =
                            acc[mi][n];
            }
            __syncthreads();
            if (kw == 0) {
                const float wA = (st == 0 || st == 3) ? (DT / 6.0f) : (DT / 3.0f);
                const float cZ = (st < 2) ? (0.5f * DT) : DT;
#pragma unroll
                for (int mi = 0; mi < 2; ++mi)
#pragma unroll
                    for (int n = 0; n < 2; ++n) {
                        f32x4 part = *reinterpret_cast<const f32x4*>(
                            SL + cw * 4096 + ((mi * 2 + n) * 64 + lane) * 16);
#pragma unroll
                        for (int j = 0; j < 4; ++j) {
                            const float kv = acc[mi][n][j] + part[j] + b2v[n];
                            float zv;
                            if (st == 0) {
                                ha[mi][n][j] = hr[mi][n][j] + wA * kv;
                                zv = hr[mi][n][j] + cZ * kv;
                            } else if (st < 3) {
                                ha[mi][n][j] += wA * kv;
                                zv = hr[mi][n][j] + cZ * kv;
                            } else {
                                hr[mi][n][j] = ha[mi][n][j] + wA * kv;
                                zv = hr[mi][n][j];
                            }
                            zG[(size_t)(r0 + 16 * mi + kq * 4 + j) * 512 +
                               (c2 + 32 * cw + 16 * n + fr)] = (__bf16)zv;
                        }
                    }
            }
        }
        __syncthreads();
        if (tid == 0)
            __hip_atomic_fetch_add(&cz[rb], 1u, __ATOMIC_RELEASE, __HIP_MEMORY_SCOPE_AGENT);
    }

    // final h -> global (fp32)
    if (kw == 0) {
#pragma unroll
        for (int mi = 0; mi < 2; ++mi)
#pragma unroll
            for (int n = 0; n < 2; ++n)
#pragma unroll
                for (int j = 0; j < 4; ++j)
                    hG[(size_t)(r0 + 16 * mi + kq * 4 + j) * 512 +
                       (c2 + 32 * cw + 16 * n + fr)] = hr[mi][n][j];
    }
}

// ---------------- out = h[:, :256] @ W_out + b_out (fp32) ----------------
__global__ __launch_bounds__(256)
void out_k(const float* __restrict__ h, const float* __restrict__ Wout,
           const float* __restrict__ bout, float* __restrict__ out) {
    const int col = threadIdx.x & 63;
    const int rg  = threadIdx.x >> 6;
    const int r0  = blockIdx.x * 16 + rg * 4;
    float a0 = 0.f, a1 = 0.f, a2 = 0.f, a3 = 0.f;
    for (int k = 0; k < 256; ++k) {
        const float w = Wout[k * OUTF + col];
        a0 += h[(r0 + 0) * LATF + k] * w;
        a1 += h[(r0 + 1) * LATF + k] * w;
        a2 += h[(r0 + 2) * LATF + k] * w;
        a3 += h[(r0 + 3) * LATF + k] * w;
    }
    const float b = bout[col];
    out[(r0 + 0) * OUTF + col] = a0 + b;
    out[(r0 + 1) * OUTF + col] = a1 + b;
    out[(r0 + 2) * OUTF + col] = a2 + b;
    out[(r0 + 3) * OUTF + col] = a3 + b;
}

extern "C" void kernel_launch(void* const* d_in, const int* in_sizes, int n_in,
                              void* d_out, int out_size, void* d_ws, size_t ws_size,
                              hipStream_t stream) {
    const float* x     = (const float*)d_in[0];
    const float* W_in  = (const float*)d_in[1];
    const float* b_in  = (const float*)d_in[2];
    const float* W1    = (const float*)d_in[3];   // (LAT+1, HID)
    const float* b1    = (const float*)d_in[4];
    const float* W2    = (const float*)d_in[5];   // (HID, LAT)
    const float* b2    = (const float*)d_in[6];
    const float* W_out = (const float*)d_in[7];   // (LAT/2, OUT)
    const float* b_out = (const float*)d_in[8];
    float* out = (float*)d_out;

    char* ws = (char*)d_ws;
    size_t off = 0;
    auto alloc = [&](size_t bytes) {
        void* p = ws + off;
        off += (bytes + 255) & ~(size_t)255;
        return p;
    };
    __bf16* xb   = (__bf16*)alloc((size_t)BB * INF * 2);
    __bf16* WinT = (__bf16*)alloc((size_t)LATF * INF * 2);   // [LAT][IN]
    __bf16* W1T  = (__bf16*)alloc((size_t)HIDF * LATF * 2);  // [HID][LAT]
    __bf16* W2T  = (__bf16*)alloc((size_t)LATF * HIDF * 2);  // [LAT][HID]
    float*  h    = (float*)alloc((size_t)BB * LATF * 4);
    __bf16* zbuf = (__bf16*)alloc((size_t)BB * LATF * 2);
    __bf16* gbuf = (__bf16*)alloc((size_t)BB * HIDF * 2);
    unsigned* cnts = (unsigned*)alloc(256);                  // cz[32] + cg[32]
    if (off > ws_size) return;

    unsigned* cz = cnts;
    unsigned* cg = cnts + 32;

    hipMemsetAsync(cnts, 0, 256, stream);
    prep_k<<<1408, dim3(32, 8), 0, stream>>>(x, xb, W_in, WinT, W1, W1T, W2, W2T);

    const float* w1last = W1 + (size_t)LATF * HIDF;  // row 512 of W1 (t coefficients)

    ode_persist<<<256, 256, 0, stream>>>(xb, WinT, W1T, W2T, b_in, b1, w1last, b2,
                                         zbuf, gbuf, h, cz, cg);

    out_k<<<BB / 16, 256, 0, stream>>>(h, W_out, b_out, out);
}

// Round 5
// 768.628 us; speedup vs baseline: 6.0939x; 2.3752x over previous
//
#include <hip/hip_runtime.h>
#include <hip/hip_bf16.h>

typedef __bf16 bf16x8 __attribute__((ext_vector_type(8)));
typedef __bf16 bf16x4 __attribute__((ext_vector_type(4)));
typedef float  f32x4  __attribute__((ext_vector_type(4)));

static constexpr int BB   = 1024;   // batch
static constexpr int INF  = 256;    // IN
static constexpr int LATF = 512;    // LAT
static constexpr int HIDF = 1024;   // HID
static constexpr int OUTF = 64;     // OUT
static constexpr float DT = 0.05f;  // (T1-T0)/N_STEPS

// normal cached staging (weights/x; producer is a prior dispatch)
__device__ __forceinline__ void gload_lds16(const __bf16* g, __bf16* l) {
    __builtin_amdgcn_global_load_lds(
        (const __attribute__((address_space(1))) void*)g,
        (__attribute__((address_space(3))) void*)l, 16, 0, 0);
}

// IF-coherent staging for cross-WG exchange data: sc0|sc1 (CPol 1|16) bypasses
// L1+L2 so reads observe other XCDs' write-through stores without any fence.
__device__ __forceinline__ void gload_lds16_sys(const __bf16* g, __bf16* l) {
    __builtin_amdgcn_global_load_lds(
        (const __attribute__((address_space(1))) void*)g,
        (__attribute__((address_space(3))) void*)l, 16, 0, 17);
}

// write-through bf16 store (sc0 sc1): lands in IF, visible chip-wide after vmcnt drain
__device__ __forceinline__ void store_bf16_sys(__bf16* p, float v) {
    const __bf16 b = (__bf16)v;
    unsigned u;
    __builtin_memcpy(&u, &b, 2);  // low 16 bits hold the bf16 pattern
    asm volatile("global_store_short %0, %1, off sc0 sc1" :: "v"(p), "v"(u) : "memory");
}

__device__ __forceinline__ void drain_vmem() {
    asm volatile("s_waitcnt vmcnt(0)" ::: "memory");
}

__device__ __forceinline__ float tanh_fast(float x) {
    float e = __expf(2.0f * x);
    return (e - 1.0f) / (e + 1.0f);
}

// tid0-only poll, RELAXED (no cache-maintenance emission, no fence needed:
// exchange data bypasses L1/L2 entirely). Caller must __syncthreads() after.
__device__ __forceinline__ void spin_ge_t0(const unsigned* p, unsigned tgt) {
    int guard = 0;
    while (__hip_atomic_load(p, __ATOMIC_RELAXED, __HIP_MEMORY_SCOPE_AGENT) < tgt) {
        __builtin_amdgcn_s_sleep(1);
        if (++guard > (1 << 23)) break;  // deterministic bailout; never hit when logic correct
    }
}

// ---------------- fused prep: x->bf16 + 3 weight transposes ----------------
__global__ __launch_bounds__(256)
void prep_k(const float* __restrict__ x, __bf16* __restrict__ xb,
            const float* __restrict__ W_in, __bf16* __restrict__ WinT,
            const float* __restrict__ W1, __bf16* __restrict__ W1T,
            const float* __restrict__ W2, __bf16* __restrict__ W2T) {
    const int b = blockIdx.x;
    const int tx = threadIdx.x, ty = threadIdx.y;
    if (b < 256) {
        const int i = b * 256 + ty * 32 + tx;
        float4 v = reinterpret_cast<const float4*>(x)[i];
        bf16x4 o;
        o[0] = (__bf16)v.x; o[1] = (__bf16)v.y; o[2] = (__bf16)v.z; o[3] = (__bf16)v.w;
        reinterpret_cast<bf16x4*>(xb)[i] = o;
        return;
    }
    const float* src; __bf16* dst; int R, C, tb;
    if (b < 384)      { src = W_in; dst = WinT; R = 256;  C = 512;  tb = b - 256; }
    else if (b < 896) { src = W1;   dst = W1T;  R = 512;  C = 1024; tb = b - 384; }
    else              { src = W2;   dst = W2T;  R = 1024; C = 512;  tb = b - 896; }
    __shared__ float tile[32][33];
    const int nbc = C / 32;
    const int c0 = (tb % nbc) * 32, r0 = (tb / nbc) * 32;
#pragma unroll
    for (int i = 0; i < 32; i += 8)
        tile[ty + i][tx] = src[(size_t)(r0 + ty + i) * C + (c0 + tx)];
    __syncthreads();
#pragma unroll
    for (int i = 0; i < 32; i += 8)
        dst[(size_t)(c0 + ty + i) * R + (r0 + tx)] = (__bf16)tile[tx][ty + i];
}

// ---------------- persistent ODE kernel ----------------
// 256 WGs (1/CU), 256 threads (4 waves). WG = (rb, slice): rb in [0,32) owns rows
// rb*32..+31; slice in [0,8): G1 cols = slice*128..+127 (HID), G2 cols = slice*64..+63 (LAT).
// Weights as persistent register B-fragments; A-tiles staged in 64KB LDS (swizzled);
// h/hacc in registers of waves kw==0. Cross-WG exchange is fence-free: data moves
// write-through (sc0 sc1) to the memory-side Infinity Cache; staging reads bypass
// L1/L2 (aux=17); flags are RELAXED agent atomics after a vmcnt drain. Round-4's
// RELEASE/ACQUIRE fences (buffer_wbl2/buffer_inv per WG per round) were ~11 us/round.
__global__ __launch_bounds__(256, 1)
void ode_persist(const __bf16* __restrict__ xb, const __bf16* __restrict__ WinT,
                 const __bf16* __restrict__ W1T, const __bf16* __restrict__ W2T,
                 const float* __restrict__ b_in, const float* __restrict__ b1,
                 const float* __restrict__ wlast, const float* __restrict__ b2,
                 __bf16* __restrict__ zG, __bf16* __restrict__ gG,
                 float* __restrict__ hG, unsigned* __restrict__ cz,
                 unsigned* __restrict__ cg) {
    __shared__ __align__(16) unsigned char SL[65536];

    const int bid   = blockIdx.x;
    const int rb    = (bid & 7) * 4 + ((bid >> 3) & 3);  // same-rb WGs share an XCD (bid%8)
    const int slice = bid >> 5;
    const int r0 = rb * 32;
    const int c1 = slice * 128;   // G1 col base (HID)
    const int c2 = slice * 64;    // G2 col base (LAT)

    const int tid  = threadIdx.x;
    const int w    = tid >> 6;    // wave 0..3
    const int lane = tid & 63;
    const int fr   = lane & 15;   // frag row/col index
    const int kq   = lane >> 4;   // k-granule 0..3
    const int cw   = w & 1;       // G2 col-half
    const int kw   = w >> 1;      // G2 k-half

    // ---- persistent register B-fragments ----
    bf16x8 b1r[2][16];  // G1: cols c1+32w+16n+fr, K=512
#pragma unroll
    for (int n = 0; n < 2; ++n)
#pragma unroll
        for (int ks = 0; ks < 16; ++ks)
            b1r[n][ks] = *reinterpret_cast<const bf16x8*>(
                W1T + (size_t)(c1 + 32 * w + 16 * n + fr) * 512 + ks * 32 + kq * 8);

    bf16x8 b2r[2][16];  // G2: cols c2+32cw+16n+fr, K-half kw*512..+511
#pragma unroll
    for (int n = 0; n < 2; ++n)
#pragma unroll
        for (int ks = 0; ks < 16; ++ks)
            b2r[n][ks] = *reinterpret_cast<const bf16x8*>(
                W2T + (size_t)(c2 + 32 * cw + 16 * n + fr) * 1024 + kw * 512 + ks * 32 + kq * 8);

    // biases (constant over dyn loop)
    float b1v[2], wlv[2], b2v[2], binv[2];
#pragma unroll
    for (int n = 0; n < 2; ++n) {
        const int colg = c1 + 32 * w + 16 * n + fr;
        b1v[n] = b1[colg];
        wlv[n] = wlast[colg];
        const int colk = c2 + 32 * cw + 16 * n + fr;
        b2v[n] = b2[colk];
        binv[n] = b_in[colk];
    }

    f32x4 hr[2][2], ha[2][2];  // h, h_acc (meaningful on kw==0 waves)

    // =========== h0 = tanh(x @ W_in + b_in) ===========
    {
#pragma unroll
        for (int i = 0; i < 4; ++i) {
            const int idx = w * 4 + i;
            const int row = idx * 2 + (lane >> 5);
            const int gam = (lane & 31) ^ (row & 7);
            gload_lds16(xb + (size_t)(r0 + row) * 256 + gam * 8,
                        (__bf16*)(SL + (size_t)idx * 1024));
        }
        bf16x8 winr[2][4];
#pragma unroll
        for (int n = 0; n < 2; ++n)
#pragma unroll
            for (int ks = 0; ks < 4; ++ks)
                winr[n][ks] = *reinterpret_cast<const bf16x8*>(
                    WinT + (size_t)(c2 + 32 * cw + 16 * n + fr) * 256 + kw * 128 + ks * 32 + kq * 8);
        __syncthreads();

        f32x4 acc[2][2];
#pragma unroll
        for (int mi = 0; mi < 2; ++mi)
#pragma unroll
            for (int n = 0; n < 2; ++n) acc[mi][n] = f32x4{0.f, 0.f, 0.f, 0.f};
#pragma unroll
        for (int ks = 0; ks < 4; ++ks) {
            bf16x8 a[2];
#pragma unroll
            for (int mi = 0; mi < 2; ++mi) {
                const int rowA = 16 * mi + fr;
                const int gk = kw * 16 + ks * 4 + kq;
                a[mi] = *reinterpret_cast<const bf16x8*>(
                    SL + (size_t)rowA * 512 + ((gk ^ (rowA & 7)) << 4));
            }
#pragma unroll
            for (int mi = 0; mi < 2; ++mi)
#pragma unroll
                for (int n = 0; n < 2; ++n)
                    acc[mi][n] = __builtin_amdgcn_mfma_f32_16x16x32_bf16(a[mi], winr[n][ks],
                                                                         acc[mi][n], 0, 0, 0);
        }
        __syncthreads();
        if (kw == 1) {
#pragma unroll
            for (int mi = 0; mi < 2; ++mi)
#pragma unroll
                for (int n = 0; n < 2; ++n)
                    *reinterpret_cast<f32x4*>(SL + cw * 4096 + ((mi * 2 + n) * 64 + lane) * 16) =
                        acc[mi][n];
        }
        __syncthreads();
        if (kw == 0) {
#pragma unroll
            for (int mi = 0; mi < 2; ++mi)
#pragma unroll
                for (int n = 0; n < 2; ++n) {
                    f32x4 part = *reinterpret_cast<const f32x4*>(
                        SL + cw * 4096 + ((mi * 2 + n) * 64 + lane) * 16);
#pragma unroll
                    for (int j = 0; j < 4; ++j) {
                        const float v = tanh_fast(acc[mi][n][j] + part[j] + binv[n]);
                        hr[mi][n][j] = v;
                        store_bf16_sys(zG + (size_t)(r0 + 16 * mi + kq * 4 + j) * 512 +
                                            (c2 + 32 * cw + 16 * n + fr), v);
                    }
                }
        }
        drain_vmem();
        __syncthreads();
        if (tid == 0)
            __hip_atomic_fetch_add(&cz[rb], 1u, __ATOMIC_RELAXED, __HIP_MEMORY_SCOPE_AGENT);
    }

    // =========== 80 dyn evaluations (20 RK4 steps x 4) ===========
    for (int it = 0; it < 80; ++it) {
        const int s4 = it >> 2, st = it & 3;
        const float t = DT * (float)s4 + ((st == 0) ? 0.f : (st == 3) ? DT : 0.5f * DT);

        // ---- G1: g = tanh(z @ W1 + b1 + t*wl), this WG's 128 cols ----
        if (tid == 0) spin_ge_t0(&cz[rb], (unsigned)(8 * (it + 1)));
        __syncthreads();
#pragma unroll
        for (int i = 0; i < 8; ++i) {
            const int row = w * 8 + i;
            const int gam = lane ^ (row & 7);
            gload_lds16_sys(zG + (size_t)(r0 + row) * 512 + gam * 8,
                            (__bf16*)(SL + (size_t)row * 1024));
        }
        __syncthreads();
        {
            f32x4 acc[2][2];
#pragma unroll
            for (int mi = 0; mi < 2; ++mi)
#pragma unroll
                for (int n = 0; n < 2; ++n) acc[mi][n] = f32x4{0.f, 0.f, 0.f, 0.f};
#pragma unroll
            for (int ks = 0; ks < 16; ++ks) {
                bf16x8 a[2];
#pragma unroll
                for (int mi = 0; mi < 2; ++mi) {
                    const int rowA = 16 * mi + fr;
                    const int gk = ks * 4 + kq;
                    a[mi] = *reinterpret_cast<const bf16x8*>(
                        SL + (size_t)rowA * 1024 + ((gk ^ (rowA & 7)) << 4));
                }
#pragma unroll
                for (int mi = 0; mi < 2; ++mi)
#pragma unroll
                    for (int n = 0; n < 2; ++n)
                        acc[mi][n] = __builtin_amdgcn_mfma_f32_16x16x32_bf16(a[mi], b1r[n][ks],
                                                                             acc[mi][n], 0, 0, 0);
            }
#pragma unroll
            for (int mi = 0; mi < 2; ++mi)
#pragma unroll
                for (int n = 0; n < 2; ++n)
#pragma unroll
                    for (int j = 0; j < 4; ++j) {
                        const float gv = tanh_fast(acc[mi][n][j] + b1v[n] + t * wlv[n]);
                        store_bf16_sys(gG + (size_t)(r0 + 16 * mi + kq * 4 + j) * 1024 +
                                            (c1 + 32 * w + 16 * n + fr), gv);
                    }
        }
        drain_vmem();
        __syncthreads();
        if (tid == 0) {
            __hip_atomic_fetch_add(&cg[rb], 1u, __ATOMIC_RELAXED, __HIP_MEMORY_SCOPE_AGENT);
            // ---- wait for all g slices ----
            spin_ge_t0(&cg[rb], (unsigned)(8 * (it + 1)));
        }
        __syncthreads();
        // stage g tile [32][1024] = 64KB
#pragma unroll
        for (int i = 0; i < 16; ++i) {
            const int idx = w * 16 + i;
            const int row = idx >> 1;
            const int p = ((idx & 1) << 6) | lane;
            const int gam = p ^ (row & 7);
            gload_lds16_sys(gG + (size_t)(r0 + row) * 1024 + gam * 8,
                            (__bf16*)(SL + (size_t)idx * 1024));
        }
        __syncthreads();
        {
            f32x4 acc[2][2];
#pragma unroll
            for (int mi = 0; mi < 2; ++mi)
#pragma unroll
                for (int n = 0; n < 2; ++n) acc[mi][n] = f32x4{0.f, 0.f, 0.f, 0.f};
#pragma unroll
            for (int ks = 0; ks < 16; ++ks) {
                bf16x8 a[2];
#pragma unroll
                for (int mi = 0; mi < 2; ++mi) {
                    const int rowA = 16 * mi + fr;
                    const int gk = kw * 64 + ks * 4 + kq;
                    a[mi] = *reinterpret_cast<const bf16x8*>(
                        SL + (size_t)rowA * 2048 + ((gk ^ (rowA & 7)) << 4));
                }
#pragma unroll
                for (int mi = 0; mi < 2; ++mi)
#pragma unroll
                    for (int n = 0; n < 2; ++n)
                        acc[mi][n] = __builtin_amdgcn_mfma_f32_16x16x32_bf16(a[mi], b2r[n][ks],
                                                                             acc[mi][n], 0, 0, 0);
            }
            __syncthreads();
            if (kw == 1) {
#pragma unroll
                for (int mi = 0; mi < 2; ++mi)
#pragma unroll
                    for (int n = 0; n < 2; ++n)
                        *reinterpret_cast<f32x4*>(SL + cw * 4096 + ((mi * 2 + n) * 64 + lane) * 16) =
                            acc[mi][n];
            }
            __syncthreads();
            if (kw == 0) {
                const float wA = (st == 0 || st == 3) ? (DT / 6.0f) : (DT / 3.0f);
                const float cZ = (st < 2) ? (0.5f * DT) : DT;
#pragma unroll
                for (int mi = 0; mi < 2; ++mi)
#pragma unroll
                    for (int n = 0; n < 2; ++n) {
                        f32x4 part = *reinterpret_cast<const f32x4*>(
                            SL + cw * 4096 + ((mi * 2 + n) * 64 + lane) * 16);
#pragma unroll
                        for (int j = 0; j < 4; ++j) {
                            const float kv = acc[mi][n][j] + part[j] + b2v[n];
                            float zv;
                            if (st == 0) {
                                ha[mi][n][j] = hr[mi][n][j] + wA * kv;
                                zv = hr[mi][n][j] + cZ * kv;
                            } else if (st < 3) {
                                ha[mi][n][j] += wA * kv;
                                zv = hr[mi][n][j] + cZ * kv;
                            } else {
                                hr[mi][n][j] = ha[mi][n][j] + wA * kv;
                                zv = hr[mi][n][j];
                            }
                            store_bf16_sys(zG + (size_t)(r0 + 16 * mi + kq * 4 + j) * 512 +
                                                (c2 + 32 * cw + 16 * n + fr), zv);
                        }
                    }
            }
        }
        drain_vmem();
        __syncthreads();
        if (tid == 0)
            __hip_atomic_fetch_add(&cz[rb], 1u, __ATOMIC_RELAXED, __HIP_MEMORY_SCOPE_AGENT);
    }

    // final h -> global (fp32; consumed by next dispatch, normal stores fine)
    if (kw == 0) {
#pragma unroll
        for (int mi = 0; mi < 2; ++mi)
#pragma unroll
            for (int n = 0; n < 2; ++n)
#pragma unroll
                for (int j = 0; j < 4; ++j)
                    hG[(size_t)(r0 + 16 * mi + kq * 4 + j) * 512 +
                       (c2 + 32 * cw + 16 * n + fr)] = hr[mi][n][j];
    }
}

// ---------------- out = h[:, :256] @ W_out + b_out (fp32) ----------------
__global__ __launch_bounds__(256)
void out_k(const float* __restrict__ h, const float* __restrict__ Wout,
           const float* __restrict__ bout, float* __restrict__ out) {
    const int col = threadIdx.x & 63;
    const int rg  = threadIdx.x >> 6;
    const int r0  = blockIdx.x * 16 + rg * 4;
    float a0 = 0.f, a1 = 0.f, a2 = 0.f, a3 = 0.f;
    for (int k = 0; k < 256; ++k) {
        const float w = Wout[k * OUTF + col];
        a0 += h[(r0 + 0) * LATF + k] * w;
        a1 += h[(r0 + 1) * LATF + k] * w;
        a2 += h[(r0 + 2) * LATF + k] * w;
        a3 += h[(r0 + 3) * LATF + k] * w;
    }
    const float b = bout[col];
    out[(r0 + 0) * OUTF + col] = a0 + b;
    out[(r0 + 1) * OUTF + col] = a1 + b;
    out[(r0 + 2) * OUTF + col] = a2 + b;
    out[(r0 + 3) * OUTF + col] = a3 + b;
}

extern "C" void kernel_launch(void* const* d_in, const int* in_sizes, int n_in,
                              void* d_out, int out_size, void* d_ws, size_t ws_size,
                              hipStream_t stream) {
    const float* x     = (const float*)d_in[0];
    const float* W_in  = (const float*)d_in[1];
    const float* b_in  = (const float*)d_in[2];
    const float* W1    = (const float*)d_in[3];   // (LAT+1, HID)
    const float* b1    = (const float*)d_in[4];
    const float* W2    = (const float*)d_in[5];   // (HID, LAT)
    const float* b2    = (const float*)d_in[6];
    const float* W_out = (const float*)d_in[7];   // (LAT/2, OUT)
    const float* b_out = (const float*)d_in[8];
    float* out = (float*)d_out;

    char* ws = (char*)d_ws;
    size_t off = 0;
    auto alloc = [&](size_t bytes) {
        void* p = ws + off;
        off += (bytes + 255) & ~(size_t)255;
        return p;
    };
    __bf16* xb   = (__bf16*)alloc((size_t)BB * INF * 2);
    __bf16* WinT = (__bf16*)alloc((size_t)LATF * INF * 2);   // [LAT][IN]
    __bf16* W1T  = (__bf16*)alloc((size_t)HIDF * LATF * 2);  // [HID][LAT]
    __bf16* W2T  = (__bf16*)alloc((size_t)LATF * HIDF * 2);  // [LAT][HID]
    float*  h    = (float*)alloc((size_t)BB * LATF * 4);
    __bf16* zbuf = (__bf16*)alloc((size_t)BB * LATF * 2);
    __bf16* gbuf = (__bf16*)alloc((size_t)BB * HIDF * 2);
    unsigned* cnts = (unsigned*)alloc(256);                  // cz[32] + cg[32]
    if (off > ws_size) return;

    unsigned* cz = cnts;
    unsigned* cg = cnts + 32;

    hipMemsetAsync(cnts, 0, 256, stream);
    prep_k<<<1408, dim3(32, 8), 0, stream>>>(x, xb, W_in, WinT, W1, W1T, W2, W2T);

    const float* w1last = W1 + (size_t)LATF * HIDF;  // row 512 of W1 (t coefficients)

    ode_persist<<<256, 256, 0, stream>>>(xb, WinT, W1T, W2T, b_in, b1, w1last, b2,
                                         zbuf, gbuf, h, cz, cg);

    out_k<<<BB / 16, 256, 0, stream>>>(h, W_out, b_out, out);
}